// Round 3
// baseline (264.491 us; speedup 1.0000x reference)
//
#include <hip/hip_runtime.h>

#define T_STEPS 200
#define OUTD 28

typedef float f2 __attribute__((ext_vector_type(2)));

// Broadcast lane SRC of each quad to all 4 lanes of the quad (one VALU op).
template<int SRC>
__device__ __forceinline__ float qb(float v) {
    return __int_as_float(__builtin_amdgcn_update_dpp(
        0, __float_as_int(v), SRC * 0x55, 0xF, 0xF, true));
}

// Pin values into VGPRs (asm output is opaque -> no rematerialization).
// Only effective in the waves_per_eu(1,1) 512-reg regime (R5 vs R6 finding).
#define PIN2(v) asm volatile("" : "+v"(v))

// Prep: Wt[t][j][c] = Wout[j][4t+c]  (per-step Wout column contiguous:
// uniform base bump 448B/step + constant lane offset).
__global__ void transpose_wout(const float* __restrict__ Wout, float* __restrict__ Wt) {
    int idx = blockIdx.x * 256 + threadIdx.x;     // 200*28*4 = 22400
    if (idx < T_STEPS * OUTD * 4) {
        int t = idx / (OUTD * 4);
        int r = idx - t * (OUTD * 4);
        int j = r >> 2, c = r & 3;
        Wt[idx] = Wout[j * 800 + 4 * t + c];
    }
}

// One layer step for one element; lane k owns unit k.
// Gate rows pre-scaled at weight-load time: i,f,o rows by -log2(e), g row by
// +2*log2(e). Activations + cell update merged over common denominators:
//   sigmoid(a_i) = 1/(1+Ei), tanh(a_g) = (Eg-1)/(Eg+1), E* = exp2(y*)
//   c' = [c*Ai*Ag + (Eg-1)*Af] * rcp(Af*Ai*Ag)       (4 exp2 + 1 rcp)
//   h  = (Ec-1) * rcp(Ao*(1+Ec)), Ec = exp2(2log2e*clamp(c'))  (1 exp2 + 1 rcp)
// 7 trans/unit-layer (~7.5 issue-cy each at 1 wave/SIMD — R2 calibration).
// hin (recurrent h) is taken by VALUE, hout by reference, so the caller can
// skew stages: L1 writes a fresh slot while L2 still reads the old one.
__device__ __forceinline__ void layer_step(const f2 (&wia)[4], const f2 (&wib)[4],
                                           const f2 (&wha)[4], const f2 (&whb)[4],
                                           const f2 (&bb)[4],
                                           f2 ina, f2 inb,
                                           f2 hin_a, f2 hin_b,
                                           f2& hout_a, f2& hout_b, float& c)
{
    float g[4];
#pragma unroll
    for (int gi = 0; gi < 4; ++gi) {
        f2 s = bb[gi];          // {bias, 0} — folded into the fma chain
        s += wia[gi] * ina;
        s += wib[gi] * inb;
        s += wha[gi] * hin_a;
        s += whb[gi] * hin_b;
        g[gi] = s.x + s.y;
    }
    float Ei = __builtin_amdgcn_exp2f(g[0]);
    float Ef = __builtin_amdgcn_exp2f(g[1]);
    float Eg = __builtin_amdgcn_exp2f(g[2]);
    float Eo = __builtin_amdgcn_exp2f(g[3]);
    float Ai = 1.0f + Ei, Af = 1.0f + Ef, Ag = 1.0f + Eg, Ao = 1.0f + Eo;
    float P   = Ai * Ag;
    float num = c * P + (Eg - 1.0f) * Af;
    c = num * __builtin_amdgcn_rcpf(P * Af);
    // tanh input clamped to +-16 (tanh(16) = 1 within fp32): overflow-proof.
    float cc = fminf(fmaxf(c, -16.0f), 16.0f);
    float Ec = __builtin_amdgcn_exp2f(2.8853900817779268f * cc);
    float ho = (Ec - 1.0f) * __builtin_amdgcn_rcpf(Ao * (1.0f + Ec));
    hout_a = f2{qb<0>(ho), qb<1>(ho)};
    hout_b = f2{qb<2>(ho), qb<3>(ho)};
}

// Skewed pipeline iteration "it = t": computes L1(t) ∥ L2(t-1) ∥ linear(t-1).
// L1(t) reads h1(t-1) from slot p and writes h1(t) to slot q; L2(t-1) also
// reads slot p — the two stages are dependence-free within the iteration,
// giving the scheduler 4 independent chains (2 elements x 2 stages) instead
// of 2. Consumes x(t) from xs and, if PREF, refills the SAME slot with
// x[tpf] (consumed 2 iterations later).
template<bool PREF>
__device__ __forceinline__ void pipe_step(
    const f2 (&wi0a)[4], const f2 (&wi0b)[4], const f2 (&wh0a)[4], const f2 (&wh0b)[4],
    const f2 (&wi1a)[4], const f2 (&wi1b)[4], const f2 (&wh1a)[4], const f2 (&wh1b)[4],
    const f2 (&b0)[4], const f2 (&b1)[4],
    f2& p1a0, f2& p1b0, f2& p1a1, f2& p1b1,      // h1(t-1) slot (read)
    f2& q1a0, f2& q1b0, f2& q1a1, f2& q1b1,      // h1(t) slot (written)
    float& c10, float& c11,
    f2& h2a0, f2& h2b0, f2& h2a1, f2& h2b1, float& c20, float& c21,
    f2 (&acc0)[7], f2 (&acc1)[7],
    float4& xs0, float4& xs1,
    const char* xp, unsigned xo0, unsigned xo1, int tpf,
    const char* wtp, unsigned w_off)
{
    // Wout column t-1 (shared by both elements).
    float4 wo[7];
#pragma unroll
    for (int jj = 0; jj < 7; ++jj)
        wo[jj] = *(const float4*)(wtp + w_off + jj * 16);

    f2 xa0 = f2{xs0.x, xs0.y}, xb0 = f2{xs0.z, xs0.w};
    f2 xa1 = f2{xs1.x, xs1.y}, xb1 = f2{xs1.z, xs1.w};

    // ---- L1(t), both elements: p -> q ----
    layer_step(wi0a, wi0b, wh0a, wh0b, b0, xa0, xb0, p1a0, p1b0, q1a0, q1b0, c10);
    layer_step(wi0a, wi0b, wh0a, wh0b, b0, xa1, xb1, p1a1, p1b1, q1a1, q1b1, c11);

    // x slots are dead now: refill with x[tpf].
    if (PREF) {
        xs0 = *(const float4*)(xp + xo0 + (size_t)tpf * 16);
        xs1 = *(const float4*)(xp + xo1 + (size_t)tpf * 16);
    }

    // ---- L2(t-1), both elements: input = p (h1(t-1)), recurrent = h2 ----
    layer_step(wi1a, wi1b, wh1a, wh1b, b1, p1a0, p1b0, h2a0, h2b0, h2a0, h2b0, c20);
    layer_step(wi1a, wi1b, wh1a, wh1b, b1, p1a1, p1b1, h2a1, h2b1, h2a1, h2b1, c21);

    // ---- linear(t-1), both elements (wo shared) ----
#pragma unroll
    for (int jj = 0; jj < 7; ++jj) {
        f2 wa = f2{wo[jj].x, wo[jj].y};
        f2 wb = f2{wo[jj].z, wo[jj].w};
        acc0[jj] += wa * h2a0; acc0[jj] += wb * h2b0;
        acc1[jj] += wa * h2a1; acc1[jj] += wb * h2b1;
    }
}

// 4 lanes per batch-element PAIR: lane k owns hidden unit k of TWO elements
// (weights shared). 65536 threads = 1024 waves = exactly 1 wave/SIMD;
// waves_per_eu(1,1) gives the allocator the 512-reg budget — the only
// regime where the weight set is honestly register-resident (VGPR=132;
// 2 waves/SIMD regimes collapse: R1 measured 161 us vs 124.5). Latency
// hiding = in-wave ILP: 2 element chains x 2 skewed stages.
__global__ __launch_bounds__(256)
__attribute__((amdgpu_waves_per_eu(1, 1)))
void lstm2_fused(const float* __restrict__ x,
                 const float* __restrict__ Wih0, const float* __restrict__ Whh0,
                 const float* __restrict__ bih0, const float* __restrict__ bhh0,
                 const float* __restrict__ Wih1, const float* __restrict__ Whh1,
                 const float* __restrict__ bih1, const float* __restrict__ bhh1,
                 const float* __restrict__ Wt,   const float* __restrict__ bout,
                 float* __restrict__ out, int batch)
{
    const int tid = blockIdx.x * 256 + threadIdx.x;
    const int quad = tid >> 2;     // element pair
    const int k = tid & 3;         // hidden unit owned by this lane
    const int e0 = quad * 2, e1 = e0 + 1;
    if (e1 >= batch) return;       // never taken (batch even)

    // ---- per-lane weights into registers (f2 pairs), gate-pre-scaled ----
    f2 wi0a[4], wi0b[4], wh0a[4], wh0b[4];
    f2 wi1a[4], wi1b[4], wh1a[4], wh1b[4];
    f2 b0[4], b1[4];
#pragma unroll
    for (int gi = 0; gi < 4; ++gi) {
        const int row = gi * 4 + k;              // rows k,4+k,8+k,12+k
        const float sc = (gi == 2) ? 2.8853900817779268f : -1.4426950408889634f;
        float4 a = ((const float4*)Wih0)[row];
        float4 c = ((const float4*)Whh0)[row];
        float4 d = ((const float4*)Wih1)[row];
        float4 e = ((const float4*)Whh1)[row];
        wi0a[gi] = f2{a.x * sc, a.y * sc}; wi0b[gi] = f2{a.z * sc, a.w * sc};
        wh0a[gi] = f2{c.x * sc, c.y * sc}; wh0b[gi] = f2{c.z * sc, c.w * sc};
        wi1a[gi] = f2{d.x * sc, d.y * sc}; wi1b[gi] = f2{d.z * sc, d.w * sc};
        wh1a[gi] = f2{e.x * sc, e.y * sc}; wh1b[gi] = f2{e.z * sc, e.w * sc};
        b0[gi] = f2{(bih0[row] + bhh0[row]) * sc, 0.0f};
        b1[gi] = f2{(bih1[row] + bhh1[row]) * sc, 0.0f};
    }
#pragma unroll
    for (int gi = 0; gi < 4; ++gi) {
        PIN2(wi0a[gi]); PIN2(wi0b[gi]); PIN2(wh0a[gi]); PIN2(wh0b[gi]);
        PIN2(wi1a[gi]); PIN2(wi1b[gi]); PIN2(wh1a[gi]); PIN2(wh1b[gi]);
        PIN2(b0[gi]);   PIN2(b1[gi]);
    }

    f2 acc0[7], acc1[7];
#pragma unroll
    for (int jj = 0; jj < 7; ++jj) {
        float bj = bout[k * 7 + jj];
        acc0[jj] = f2{bj, 0.0f};
        acc1[jj] = f2{bj, 0.0f};
    }

    // h1 double-slot (A even-t outputs... roles swap each iteration).
    f2 h1Aa0 = f2{0,0}, h1Ab0 = f2{0,0}, h1Aa1 = f2{0,0}, h1Ab1 = f2{0,0};
    f2 h1Ba0 = f2{0,0}, h1Bb0 = f2{0,0}, h1Ba1 = f2{0,0}, h1Bb1 = f2{0,0};
    f2 h2a0 = f2{0,0}, h2b0 = f2{0,0}, h2a1 = f2{0,0}, h2b1 = f2{0,0};
    float c10 = 0.0f, c20 = 0.0f, c11 = 0.0f, c21 = 0.0f;

    // Uniform bases (SALU-advanced) + constant per-lane byte offsets.
    const char* xp  = (const char*)x;
    const unsigned xo0 = (unsigned)e0 * 3200u;        // e * 200*4*4B
    const unsigned xo1 = (unsigned)e1 * 3200u;
    const char* wtp = (const char*)Wt;                // + 448 each iteration
    const unsigned w_off = (unsigned)k * 112u;        // k*7 rows * 16B

    // Slot S0 (xv) holds even steps' x, S1 (xn) odd steps'.
    float4 xv0 = *(const float4*)(xp + xo0);
    float4 xv1 = *(const float4*)(xp + xo1);
    float4 xn0 = *(const float4*)(xp + xo0 + 16);
    float4 xn1 = *(const float4*)(xp + xo1 + 16);

    // ---- prologue: L1(0) from zero state -> slot A; refill S0 with x2 ----
    {
        f2 z = f2{0, 0};
        f2 xa0 = f2{xv0.x, xv0.y}, xb0 = f2{xv0.z, xv0.w};
        f2 xa1 = f2{xv1.x, xv1.y}, xb1 = f2{xv1.z, xv1.w};
        layer_step(wi0a, wi0b, wh0a, wh0b, b0, xa0, xb0, z, z, h1Aa0, h1Ab0, c10);
        layer_step(wi0a, wi0b, wh0a, wh0b, b0, xa1, xb1, z, z, h1Aa1, h1Ab1, c11);
        xv0 = *(const float4*)(xp + xo0 + 2 * 16);
        xv1 = *(const float4*)(xp + xo1 + 2 * 16);
    }

    // ---- main loop: iterations t=1..196 as 98 unrolled pairs ----
    // odd t: p=A, q=B, consume S1;  even t: p=B, q=A, consume S0.
    for (int t = 1; t <= 195; t += 2) {
        pipe_step<true>(wi0a, wi0b, wh0a, wh0b, wi1a, wi1b, wh1a, wh1b, b0, b1,
                        h1Aa0, h1Ab0, h1Aa1, h1Ab1,
                        h1Ba0, h1Bb0, h1Ba1, h1Bb1,
                        c10, c11, h2a0, h2b0, h2a1, h2b1, c20, c21,
                        acc0, acc1, xn0, xn1, xp, xo0, xo1, t + 2, wtp, w_off);
        wtp += OUTD * 16;
        pipe_step<true>(wi0a, wi0b, wh0a, wh0b, wi1a, wi1b, wh1a, wh1b, b0, b1,
                        h1Ba0, h1Bb0, h1Ba1, h1Bb1,
                        h1Aa0, h1Ab0, h1Aa1, h1Ab1,
                        c10, c11, h2a0, h2b0, h2a1, h2b1, c20, c21,
                        acc0, acc1, xv0, xv1, xp, xo0, xo1, t + 3, wtp, w_off);
        wtp += OUTD * 16;
    }
    // it=197 (p=A,q=B, consume S1, prefetch x199 -> S1)
    pipe_step<true>(wi0a, wi0b, wh0a, wh0b, wi1a, wi1b, wh1a, wh1b, b0, b1,
                    h1Aa0, h1Ab0, h1Aa1, h1Ab1,
                    h1Ba0, h1Bb0, h1Ba1, h1Bb1,
                    c10, c11, h2a0, h2b0, h2a1, h2b1, c20, c21,
                    acc0, acc1, xn0, xn1, xp, xo0, xo1, 199, wtp, w_off);
    wtp += OUTD * 16;
    // it=198 (p=B,q=A, consume S0, no prefetch)
    pipe_step<false>(wi0a, wi0b, wh0a, wh0b, wi1a, wi1b, wh1a, wh1b, b0, b1,
                     h1Ba0, h1Bb0, h1Ba1, h1Bb1,
                     h1Aa0, h1Ab0, h1Aa1, h1Ab1,
                     c10, c11, h2a0, h2b0, h2a1, h2b1, c20, c21,
                     acc0, acc1, xv0, xv1, xp, xo0, xo1, 0, wtp, w_off);
    wtp += OUTD * 16;
    // it=199 (p=A,q=B, consume S1, no prefetch)
    pipe_step<false>(wi0a, wi0b, wh0a, wh0b, wi1a, wi1b, wh1a, wh1b, b0, b1,
                     h1Aa0, h1Ab0, h1Aa1, h1Ab1,
                     h1Ba0, h1Bb0, h1Ba1, h1Bb1,
                     c10, c11, h2a0, h2b0, h2a1, h2b1, c20, c21,
                     acc0, acc1, xn0, xn1, xp, xo0, xo1, 0, wtp, w_off);
    wtp += OUTD * 16;
    // ---- epilogue: L2(199) (input = slot B) + linear(199) ----
    {
        float4 wo[7];
#pragma unroll
        for (int jj = 0; jj < 7; ++jj)
            wo[jj] = *(const float4*)(wtp + w_off + jj * 16);
        layer_step(wi1a, wi1b, wh1a, wh1b, b1, h1Ba0, h1Bb0, h2a0, h2b0, h2a0, h2b0, c20);
        layer_step(wi1a, wi1b, wh1a, wh1b, b1, h1Ba1, h1Bb1, h2a1, h2b1, h2a1, h2b1, c21);
#pragma unroll
        for (int jj = 0; jj < 7; ++jj) {
            f2 wa = f2{wo[jj].x, wo[jj].y};
            f2 wb = f2{wo[jj].z, wo[jj].w};
            acc0[jj] += wa * h2a0; acc0[jj] += wb * h2b0;
            acc1[jj] += wa * h2a1; acc1[jj] += wb * h2b1;
        }
    }

    float* op0 = out + (size_t)e0 * OUTD + k * 7;
    float* op1 = out + (size_t)e1 * OUTD + k * 7;
#pragma unroll
    for (int jj = 0; jj < 7; ++jj) {
        op0[jj] = acc0[jj].x + acc0[jj].y;
        op1[jj] = acc1[jj].x + acc1[jj].y;
    }
}

extern "C" void kernel_launch(void* const* d_in, const int* in_sizes, int n_in,
                              void* d_out, int out_size, void* d_ws, size_t ws_size,
                              hipStream_t stream) {
    const float* x    = (const float*)d_in[0];
    const float* Wih0 = (const float*)d_in[1];
    const float* Whh0 = (const float*)d_in[2];
    const float* bih0 = (const float*)d_in[3];
    const float* bhh0 = (const float*)d_in[4];
    const float* Wih1 = (const float*)d_in[5];
    const float* Whh1 = (const float*)d_in[6];
    const float* bih1 = (const float*)d_in[7];
    const float* bhh1 = (const float*)d_in[8];
    const float* Wout = (const float*)d_in[9];
    const float* bout = (const float*)d_in[10];
    float* out = (float*)d_out;
    float* Wt  = (float*)d_ws;      // 200*28*4 floats = 89.6 KB

    transpose_wout<<<(T_STEPS * OUTD * 4 + 255) / 256, 256, 0, stream>>>(Wout, Wt);

    const int batch = in_sizes[0] / (T_STEPS * 4);   // 32768
    const int threads = (batch / 2) * 4;             // 65536
    const int grid = threads / 256;                  // 256
    lstm2_fused<<<grid, 256, 0, stream>>>(
        x, Wih0, Whh0, bih0, bhh0, Wih1, Whh1, bih1, bhh1, Wt, bout, out, batch);
}

// Round 4
// 234.312 us; speedup vs baseline: 1.1288x; 1.1288x over previous
//
#include <hip/hip_runtime.h>

#define T_STEPS 200
#define OUTD 28

typedef float f2 __attribute__((ext_vector_type(2)));

// Broadcast lane SRC of each quad to all 4 lanes of the quad (one VALU op).
template<int SRC>
__device__ __forceinline__ float qb(float v) {
    return __int_as_float(__builtin_amdgcn_update_dpp(
        0, __float_as_int(v), SRC * 0x55, 0xF, 0xF, true));
}

// Pin values into VGPRs (asm output is opaque -> no rematerialization).
// Only effective in the waves_per_eu(1,1) 512-reg regime.
#define PIN2(v) asm volatile("" : "+v"(v))

// Prep: Wt[t][j][c] = Wout[j][4t+c]  (per-step Wout column contiguous:
// uniform base bump 448B/step + constant lane offset).
__global__ void transpose_wout(const float* __restrict__ Wout, float* __restrict__ Wt) {
    int idx = blockIdx.x * 256 + threadIdx.x;     // 200*28*4 = 22400
    if (idx < T_STEPS * OUTD * 4) {
        int t = idx / (OUTD * 4);
        int r = idx - t * (OUTD * 4);
        int j = r >> 2, c = r & 3;
        Wt[idx] = Wout[j * 800 + 4 * t + c];
    }
}

// One layer step for BOTH elements of the pair, statement-interleaved.
// Gate rows pre-scaled at weight-load time: i,f,o rows by -log2(e), g row by
// +2*log2(e). Activations + cell update merged over common denominators:
//   sigmoid(a_i) = 1/(1+Ei), tanh(a_g) = (Eg-1)/(Eg+1), E* = exp2(y*)
//   c' = [c*Ai*Ag + (Eg-1)*Af] * rcp(Af*Ai*Ag)       (4 exp2 + 1 rcp)
//   h  = (Ec-1) * rcp(Ao*(1+Ec)), Ec = exp2(2log2e*clamp(c'))  (1 exp2 + 1 rcp)
// 7 trans/unit-layer/element (~7.5+ issue-cy each at 1 wave/SIMD — R2
// calibration). The two element chains are interleaved statement-by-
// statement so every other instruction is independent — the in-order list
// scheduler gets ILP locally instead of having to hoist across two inlined
// 40-instruction blocks (R2's residual 420 idle cy/step).
__device__ __forceinline__ void layer_step2(const f2 (&wia)[4], const f2 (&wib)[4],
                                            const f2 (&wha)[4], const f2 (&whb)[4],
                                            const f2 (&bb)[4],
                                            f2 ina0, f2 inb0, f2 ina1, f2 inb1,
                                            f2& ha0, f2& hb0, f2& ha1, f2& hb1,
                                            float& c0, float& c1)
{
    float g0[4], g1[4];
#pragma unroll
    for (int gi = 0; gi < 4; ++gi) {
        f2 s0 = bb[gi];            // {bias, 0} — folded into the fma chain
        f2 s1 = bb[gi];
        s0 += wia[gi] * ina0;  s1 += wia[gi] * ina1;
        s0 += wib[gi] * inb0;  s1 += wib[gi] * inb1;
        s0 += wha[gi] * ha0;   s1 += wha[gi] * ha1;   // h enters last (fresh)
        s0 += whb[gi] * hb0;   s1 += whb[gi] * hb1;
        g0[gi] = s0.x + s0.y;  g1[gi] = s1.x + s1.y;
    }
    float Ei0 = __builtin_amdgcn_exp2f(g0[0]), Ei1 = __builtin_amdgcn_exp2f(g1[0]);
    float Ef0 = __builtin_amdgcn_exp2f(g0[1]), Ef1 = __builtin_amdgcn_exp2f(g1[1]);
    float Eg0 = __builtin_amdgcn_exp2f(g0[2]), Eg1 = __builtin_amdgcn_exp2f(g1[2]);
    float Eo0 = __builtin_amdgcn_exp2f(g0[3]), Eo1 = __builtin_amdgcn_exp2f(g1[3]);
    float Ai0 = 1.0f + Ei0,  Ai1 = 1.0f + Ei1;
    float Af0 = 1.0f + Ef0,  Af1 = 1.0f + Ef1;
    float Ag0 = 1.0f + Eg0,  Ag1 = 1.0f + Eg1;
    float Ao0 = 1.0f + Eo0,  Ao1 = 1.0f + Eo1;
    float P0 = Ai0 * Ag0,    P1 = Ai1 * Ag1;
    float n0 = c0 * P0 + (Eg0 - 1.0f) * Af0;
    float n1 = c1 * P1 + (Eg1 - 1.0f) * Af1;
    float r0 = __builtin_amdgcn_rcpf(P0 * Af0);
    float r1 = __builtin_amdgcn_rcpf(P1 * Af1);
    c0 = n0 * r0;
    c1 = n1 * r1;
    // tanh input clamped to +-16 (tanh(16) = 1 within fp32): overflow-proof.
    float cc0 = __builtin_amdgcn_fmed3f(c0, -16.0f, 16.0f);
    float cc1 = __builtin_amdgcn_fmed3f(c1, -16.0f, 16.0f);
    float Ec0 = __builtin_amdgcn_exp2f(2.8853900817779268f * cc0);
    float Ec1 = __builtin_amdgcn_exp2f(2.8853900817779268f * cc1);
    float q0 = __builtin_amdgcn_rcpf(Ao0 * (1.0f + Ec0));
    float q1 = __builtin_amdgcn_rcpf(Ao1 * (1.0f + Ec1));
    float ho0 = (Ec0 - 1.0f) * q0;
    float ho1 = (Ec1 - 1.0f) * q1;
    ha0 = f2{qb<0>(ho0), qb<1>(ho0)};
    ha1 = f2{qb<0>(ho1), qb<1>(ho1)};
    hb0 = f2{qb<2>(ho0), qb<3>(ho0)};
    hb1 = f2{qb<2>(ho1), qb<3>(ho1)};
}

// One full timestep for both elements of this lane's pair.
// Consumes x from (xs0,xs1) and, if PREF, refills the SAME slots with
// x[tpf] (issued right after layer-1's last read -> zero rotation movs,
// ~1.5 steps of latency cover).
template<bool PREF>
__device__ __forceinline__ void full_step(
    const f2 (&wi0a)[4], const f2 (&wi0b)[4], const f2 (&wh0a)[4], const f2 (&wh0b)[4],
    const f2 (&wi1a)[4], const f2 (&wi1b)[4], const f2 (&wh1a)[4], const f2 (&wh1b)[4],
    const f2 (&b0)[4], const f2 (&b1)[4],
    f2& h1a0, f2& h1b0, f2& h2a0, f2& h2b0, float& c10, float& c20,
    f2& h1a1, f2& h1b1, f2& h2a1, f2& h2b1, float& c11, float& c21,
    f2 (&acc0)[7], f2 (&acc1)[7],
    float4& xs0, float4& xs1,
    const char* xp, unsigned xo0, unsigned xo1, int tpf,
    const char* wtp, unsigned w_off)
{
    // This step's Wout column (shared by both elements).
    float4 wo[7];
#pragma unroll
    for (int jj = 0; jj < 7; ++jj)
        wo[jj] = *(const float4*)(wtp + w_off + jj * 16);

    f2 xa0 = f2{xs0.x, xs0.y}, xb0 = f2{xs0.z, xs0.w};
    f2 xa1 = f2{xs1.x, xs1.y}, xb1 = f2{xs1.z, xs1.w};

    // ---- layer 1, both elements, interleaved ----
    layer_step2(wi0a, wi0b, wh0a, wh0b, b0,
                xa0, xb0, xa1, xb1,
                h1a0, h1b0, h1a1, h1b1, c10, c11);

    // x slots are dead now: refill with x[tpf] (consumed 2 steps later).
    if (PREF) {
        xs0 = *(const float4*)(xp + xo0 + (size_t)tpf * 16);
        xs1 = *(const float4*)(xp + xo1 + (size_t)tpf * 16);
    }

    // ---- layer 2, both elements, interleaved ----
    layer_step2(wi1a, wi1b, wh1a, wh1b, b1,
                h1a0, h1b0, h1a1, h1b1,
                h2a0, h2b0, h2a1, h2b1, c20, c21);

    // ---- fused linear, both elements (wo shared) ----
#pragma unroll
    for (int jj = 0; jj < 7; ++jj) {
        f2 wa = f2{wo[jj].x, wo[jj].y};
        f2 wb = f2{wo[jj].z, wo[jj].w};
        acc0[jj] += wa * h2a0; acc0[jj] += wb * h2b0;
        acc1[jj] += wa * h2a1; acc1[jj] += wb * h2b1;
    }
}

// 4 lanes per batch-element PAIR: lane k owns hidden unit k of TWO elements
// (weights shared). 65536 threads = 1024 waves = exactly 1 wave/SIMD;
// waves_per_eu(1,1) gives the allocator the 512-reg budget — the only
// regime where the weight set is honestly register-resident (2 waves/SIMD
// regimes collapse: R1 measured 161 us vs 124.5 — 96-VGPR weight reloads).
// Latency hiding = in-wave ILP from the two interleaved element chains.
__global__ __launch_bounds__(256)
__attribute__((amdgpu_waves_per_eu(1, 1)))
void lstm2_fused(const float* __restrict__ x,
                 const float* __restrict__ Wih0, const float* __restrict__ Whh0,
                 const float* __restrict__ bih0, const float* __restrict__ bhh0,
                 const float* __restrict__ Wih1, const float* __restrict__ Whh1,
                 const float* __restrict__ bih1, const float* __restrict__ bhh1,
                 const float* __restrict__ Wt,   const float* __restrict__ bout,
                 float* __restrict__ out, int batch)
{
    const int tid = blockIdx.x * 256 + threadIdx.x;
    const int quad = tid >> 2;     // element pair
    const int k = tid & 3;         // hidden unit owned by this lane
    const int e0 = quad * 2, e1 = e0 + 1;
    if (e1 >= batch) return;       // never taken (batch even)

    // ---- per-lane weights into registers (f2 pairs), gate-pre-scaled ----
    f2 wi0a[4], wi0b[4], wh0a[4], wh0b[4];
    f2 wi1a[4], wi1b[4], wh1a[4], wh1b[4];
    f2 b0[4], b1[4];
#pragma unroll
    for (int gi = 0; gi < 4; ++gi) {
        const int row = gi * 4 + k;              // rows k,4+k,8+k,12+k
        const float sc = (gi == 2) ? 2.8853900817779268f : -1.4426950408889634f;
        float4 a = ((const float4*)Wih0)[row];
        float4 c = ((const float4*)Whh0)[row];
        float4 d = ((const float4*)Wih1)[row];
        float4 e = ((const float4*)Whh1)[row];
        wi0a[gi] = f2{a.x * sc, a.y * sc}; wi0b[gi] = f2{a.z * sc, a.w * sc};
        wh0a[gi] = f2{c.x * sc, c.y * sc}; wh0b[gi] = f2{c.z * sc, c.w * sc};
        wi1a[gi] = f2{d.x * sc, d.y * sc}; wi1b[gi] = f2{d.z * sc, d.w * sc};
        wh1a[gi] = f2{e.x * sc, e.y * sc}; wh1b[gi] = f2{e.z * sc, e.w * sc};
        b0[gi] = f2{(bih0[row] + bhh0[row]) * sc, 0.0f};
        b1[gi] = f2{(bih1[row] + bhh1[row]) * sc, 0.0f};
    }
#pragma unroll
    for (int gi = 0; gi < 4; ++gi) {
        PIN2(wi0a[gi]); PIN2(wi0b[gi]); PIN2(wh0a[gi]); PIN2(wh0b[gi]);
        PIN2(wi1a[gi]); PIN2(wi1b[gi]); PIN2(wh1a[gi]); PIN2(wh1b[gi]);
        PIN2(b0[gi]);   PIN2(b1[gi]);
    }

    f2 acc0[7], acc1[7];
#pragma unroll
    for (int jj = 0; jj < 7; ++jj) {
        float bj = bout[k * 7 + jj];
        acc0[jj] = f2{bj, 0.0f};
        acc1[jj] = f2{bj, 0.0f};
    }

    f2 h1a0 = f2{0,0}, h1b0 = f2{0,0}, h2a0 = f2{0,0}, h2b0 = f2{0,0};
    f2 h1a1 = f2{0,0}, h1b1 = f2{0,0}, h2a1 = f2{0,0}, h2b1 = f2{0,0};
    float c10 = 0.0f, c20 = 0.0f, c11 = 0.0f, c21 = 0.0f;

    // Uniform bases (SALU-advanced) + constant per-lane byte offsets.
    const char* xp  = (const char*)x;
    const unsigned xo0 = (unsigned)e0 * 3200u;        // e * 200*4*4B
    const unsigned xo1 = (unsigned)e1 * 3200u;
    const char* wtp = (const char*)Wt;                // + 448 each step
    const unsigned w_off = (unsigned)k * 112u;        // k*7 rows * 16B

    // Slot A holds even steps' x, slot B odd steps'.
    float4 xv0 = *(const float4*)(xp + xo0);
    float4 xv1 = *(const float4*)(xp + xo1);
    float4 xn0 = *(const float4*)(xp + xo0 + 16);
    float4 xn1 = *(const float4*)(xp + xo1 + 16);

    // Main loop: unroll x2 with slot-role swap (zero rotation movs).
    for (int t = 0; t < T_STEPS - 2; t += 2) {
        full_step<true>(wi0a, wi0b, wh0a, wh0b, wi1a, wi1b, wh1a, wh1b, b0, b1,
                        h1a0, h1b0, h2a0, h2b0, c10, c20,
                        h1a1, h1b1, h2a1, h2b1, c11, c21,
                        acc0, acc1, xv0, xv1, xp, xo0, xo1, t + 2, wtp, w_off);
        wtp += OUTD * 16;
        full_step<true>(wi0a, wi0b, wh0a, wh0b, wi1a, wi1b, wh1a, wh1b, b0, b1,
                        h1a0, h1b0, h2a0, h2b0, c10, c20,
                        h1a1, h1b1, h2a1, h2b1, c11, c21,
                        acc0, acc1, xn0, xn1, xp, xo0, xo1, t + 3, wtp, w_off);
        wtp += OUTD * 16;
    }
    // Epilogue: steps 198 (slot A) and 199 (slot B), no prefetch.
    full_step<false>(wi0a, wi0b, wh0a, wh0b, wi1a, wi1b, wh1a, wh1b, b0, b1,
                     h1a0, h1b0, h2a0, h2b0, c10, c20,
                     h1a1, h1b1, h2a1, h2b1, c11, c21,
                     acc0, acc1, xv0, xv1, xp, xo0, xo1, 0, wtp, w_off);
    wtp += OUTD * 16;
    full_step<false>(wi0a, wi0b, wh0a, wh0b, wi1a, wi1b, wh1a, wh1b, b0, b1,
                     h1a0, h1b0, h2a0, h2b0, c10, c20,
                     h1a1, h1b1, h2a1, h2b1, c11, c21,
                     acc0, acc1, xn0, xn1, xp, xo0, xo1, 0, wtp, w_off);

    float* op0 = out + (size_t)e0 * OUTD + k * 7;
    float* op1 = out + (size_t)e1 * OUTD + k * 7;
#pragma unroll
    for (int jj = 0; jj < 7; ++jj) {
        op0[jj] = acc0[jj].x + acc0[jj].y;
        op1[jj] = acc1[jj].x + acc1[jj].y;
    }
}

extern "C" void kernel_launch(void* const* d_in, const int* in_sizes, int n_in,
                              void* d_out, int out_size, void* d_ws, size_t ws_size,
                              hipStream_t stream) {
    const float* x    = (const float*)d_in[0];
    const float* Wih0 = (const float*)d_in[1];
    const float* Whh0 = (const float*)d_in[2];
    const float* bih0 = (const float*)d_in[3];
    const float* bhh0 = (const float*)d_in[4];
    const float* Wih1 = (const float*)d_in[5];
    const float* Whh1 = (const float*)d_in[6];
    const float* bih1 = (const float*)d_in[7];
    const float* bhh1 = (const float*)d_in[8];
    const float* Wout = (const float*)d_in[9];
    const float* bout = (const float*)d_in[10];
    float* out = (float*)d_out;
    float* Wt  = (float*)d_ws;      // 200*28*4 floats = 89.6 KB

    transpose_wout<<<(T_STEPS * OUTD * 4 + 255) / 256, 256, 0, stream>>>(Wout, Wt);

    const int batch = in_sizes[0] / (T_STEPS * 4);   // 32768
    const int threads = (batch / 2) * 4;             // 65536
    const int grid = threads / 256;                  // 256
    lstm2_fused<<<grid, 256, 0, stream>>>(
        x, Wih0, Whh0, bih0, bhh0, Wih1, Whh1, bih1, bhh1, Wt, bout, out, batch);
}